// Round 2
// baseline (2188.573 us; speedup 1.0000x reference)
//
#include <hip/hip_runtime.h>

// StimulusModel: per-element 256-step recurrence, FLOAT32 in/out.
//   g      = 2 * sigmoid(u - u_trigger)           (BETA=1, G_MAX=2)
//   u_next = clip(u + 0.05 - 0.1*g, 0.01, 0.2)
// Outputs concatenated: u_hist[steps][B] ++ g_hist[steps][B], f32.
// Write-bound: 2 GiB of f32 stores -> target ~340-420us @ ~6.3 TB/s.

#define VEC 4  // f32 elements per thread -> one float4 (16B) store per array per step

__global__ __launch_bounds__(256) void stimulus_kernel(
    const float* __restrict__ u_init,   // [B] f32
    const float* __restrict__ ut_p,     // [1] f32
    float* __restrict__ u_hist,         // [steps][B] f32
    float* __restrict__ g_hist,         // [steps][B] f32
    int B, int steps)
{
    const int tid = blockIdx.x * blockDim.x + threadIdx.x;
    const size_t base = (size_t)tid * VEC;
    if (base >= (size_t)B) return;

    const float ut = ut_p[0];

    float4 in = *(const float4*)(u_init + base);
    float u[VEC] = {in.x, in.y, in.z, in.w};

    float* up = u_hist + base;
    float* gp = g_hist + base;

    for (int t = 0; t < steps; ++t) {
        float g[VEC];
        #pragma unroll
        for (int j = 0; j < VEC; ++j) {
            // g = 2*sigmoid(u - ut) = 2 / (1 + exp(-(u - ut)))
            float e = __expf(ut - u[j]);
            g[j] = 2.0f / (1.0f + e);
            float un = u[j] + (0.05f - 0.1f * g[j]);
            un = fminf(fmaxf(un, 0.01f), 0.2f);   // clip to [U_MIN, U_MAX]
            u[j] = un;
        }
        float4 uv = make_float4(u[0], u[1], u[2], u[3]);
        float4 gv = make_float4(g[0], g[1], g[2], g[3]);
        *(float4*)up = uv;   // 16B coalesced store
        *(float4*)gp = gv;
        up += B;
        gp += B;
    }
}

extern "C" void kernel_launch(void* const* d_in, const int* in_sizes, int n_in,
                              void* d_out, int out_size, void* d_ws, size_t ws_size,
                              hipStream_t stream) {
    const float* u_init = (const float*)d_in[0];
    const float* ut     = (const float*)d_in[1];
    const int B = in_sizes[0];
    const int steps = out_size / (2 * B);   // out = u_hist ++ g_hist

    float* u_hist = (float*)d_out;
    float* g_hist = u_hist + (size_t)steps * (size_t)B;

    const int threads = (B + VEC - 1) / VEC;
    const int block = 256;
    const int grid = (threads + block - 1) / block;
    hipLaunchKernelGGL(stimulus_kernel, dim3(grid), dim3(block), 0, stream,
                       u_init, ut, u_hist, g_hist, B, steps);
}